// Round 9
// baseline (116.581 us; speedup 1.0000x reference)
//
#include <hip/hip_runtime.h>

#define BATCH 16
#define SEQ   4096
#define DIM   64
#define WIN   512

constexpr int BM = 64;        // q rows per block (4 waves x 16 q-rows) -> 4 blk/CU
constexpr int BN = 64;        // keys per tile
constexpr int NTHREADS = 256; // 4 waves
constexpr int KS  = DIM + 8;  // Ksh row stride (f16)
constexpr int VSP = 20;       // V panel row stride (16 keys + 4 pad) -> low-conflict
constexpr int OS  = DIM + 4;  // Osh row stride (f32)
constexpr int KBYTES   = BN * KS * 2;        // 9216
constexpr int VPANEL   = DIM * VSP * 2;      // 2560 B per 16-key panel
constexpr int VBYTES   = (BN / 16) * VPANEL; // 10240
constexpr int BUFBYTES = KBYTES + VBYTES;    // 19456
constexpr int SMEMBYTES = 2 * BUFBYTES;      // 38912 B; x4 blocks = 155648 <= 160K

constexpr float QSCALE  = 0.125f * 1.44269504088896340736f;
constexpr float MASKVAL = -3.0e38f;   // << m_run init so masked lanes give p = 0
constexpr float DEFER_THR = 8.0f;

typedef _Float16 f16x2 __attribute__((ext_vector_type(2)));
typedef _Float16 f16x4 __attribute__((ext_vector_type(4)));
typedef _Float16 f16x8 __attribute__((ext_vector_type(8)));
typedef float    f32x4 __attribute__((ext_vector_type(4)));

__device__ __forceinline__ f16x2 pk2(float a, float b) {
    return __builtin_bit_cast(f16x2, __builtin_amdgcn_cvt_pkrtz(a, b));
}

// per-thread prefetch: 4 adjacent K rows + 4 adjacent V rows, one float4 col chunk
struct Pref {
    float4 k0, k1, k2, k3;
    float4 v0, v1, v2, v3;
};

__device__ __forceinline__ void load_tile(Pref& p, const float* __restrict__ kb,
                                          const float* __restrict__ vb,
                                          int kbase, int row4, int c4) {
    const size_t g = (size_t)(kbase + row4) * DIM + c4;
    p.k0 = *(const float4*)&kb[g + 0 * DIM];
    p.k1 = *(const float4*)&kb[g + 1 * DIM];
    p.k2 = *(const float4*)&kb[g + 2 * DIM];
    p.k3 = *(const float4*)&kb[g + 3 * DIM];
    p.v0 = *(const float4*)&vb[g + 0 * DIM];
    p.v1 = *(const float4*)&vb[g + 1 * DIM];
    p.v2 = *(const float4*)&vb[g + 2 * DIM];
    p.v3 = *(const float4*)&vb[g + 3 * DIM];
}

__device__ __forceinline__ void stage_tile(char* __restrict__ buf, const Pref& p,
                                           int row4, int c4) {
    _Float16* Ksh = (_Float16*)buf;
    _Float16* Vsh = (_Float16*)(buf + KBYTES);
    union { f16x4 v; f16x2 h[2]; } u;
    u.h[0] = pk2(p.k0.x, p.k0.y); u.h[1] = pk2(p.k0.z, p.k0.w);
    *(f16x4*)&Ksh[(row4 + 0) * KS + c4] = u.v;
    u.h[0] = pk2(p.k1.x, p.k1.y); u.h[1] = pk2(p.k1.z, p.k1.w);
    *(f16x4*)&Ksh[(row4 + 1) * KS + c4] = u.v;
    u.h[0] = pk2(p.k2.x, p.k2.y); u.h[1] = pk2(p.k2.z, p.k2.w);
    *(f16x4*)&Ksh[(row4 + 2) * KS + c4] = u.v;
    u.h[0] = pk2(p.k3.x, p.k3.y); u.h[1] = pk2(p.k3.z, p.k3.w);
    *(f16x4*)&Ksh[(row4 + 3) * KS + c4] = u.v;
    // V panels: panel = key>>4, within-panel key = key&15; 4 adjacent keys at
    // fixed d -> one 8B f16x4 store; panel row stride 20 f16 -> low conflicts
    const int pbase = (row4 >> 4) * (DIM * VSP) + (row4 & 15);
    const float* f0 = (const float*)&p.v0;
    const float* f1 = (const float*)&p.v1;
    const float* f2 = (const float*)&p.v2;
    const float* f3 = (const float*)&p.v3;
    #pragma unroll
    for (int j = 0; j < 4; ++j) {
        u.h[0] = pk2(f0[j], f1[j]);
        u.h[1] = pk2(f2[j], f3[j]);
        *(f16x4*)&Vsh[pbase + (c4 + j) * VSP] = u.v;
    }
}

// (256,4): blocks/CU semantics -> 16 waves/CU -> 128 VGPR cap; waves/EU -> same.
// LDS limits residency to 4 blocks/CU (155.6 KB); we need ~70 VGPR -> no spill.
__global__ __launch_bounds__(NTHREADS, 4)
void swa_kernel(const float* __restrict__ qg, const float* __restrict__ kg,
                const float* __restrict__ vg, float* __restrict__ outg) {
    __shared__ __align__(16) char smem[SMEMBYTES];
    float* Osh = (float*)smem;

    const int tid  = threadIdx.x;
    const int lane = tid & 63;
    const int wave = tid >> 6;     // 0..3
    const int lr   = lane & 15;
    const int quad = lane >> 4;

    // chunked XCD swizzle: 8 consecutive qblks of one batch per XCD chunk
    static_assert(SEQ / BM == 64 && BATCH == 16, "swizzle assumes 1024 blocks");
    const int lin    = blockIdx.x + (SEQ / BM) * blockIdx.y;  // 0..1023
    const int xcd    = lin & 7;
    const int slot   = lin >> 3;           // 0..127
    const int member = slot & 7;
    const int gchunk = (slot >> 3) * 8 + xcd;      // bijective 0..127
    const int b      = gchunk >> 3;                // 16 batches
    const int qblk   = (gchunk & 7) * 8 + member;  // 64 qblks

    const int qrow0 = qblk * BM;
    const int wr0   = qrow0 + wave * 16;
    const int q     = wr0 + lr;          // this lane's q column (S^T layout)

    const float* qb = qg + (size_t)b * SEQ * DIM;
    const float* kb = kg + (size_t)b * SEQ * DIM;
    const float* vb = vg + (size_t)b * SEQ * DIM;
    float*       ob = outg + (size_t)b * SEQ * DIM;

    const int row4 = (tid >> 4) * 4;      // staging: 4 adjacent rows / thread
    const int c4   = (tid & 15) * 4;

    // ---- Q B-frags straight from global into registers ----
    const float* qp = qb + (size_t)q * DIM + quad * 8;
    const float4 a0 = *(const float4*)(qp + 0);
    const float4 a1 = *(const float4*)(qp + 4);
    const float4 a2 = *(const float4*)(qp + 32);
    const float4 a3 = *(const float4*)(qp + 36);
    union { f16x8 v; f16x2 h[4]; } uq0, uq1;
    uq0.h[0] = pk2(a0.x * QSCALE, a0.y * QSCALE);
    uq0.h[1] = pk2(a0.z * QSCALE, a0.w * QSCALE);
    uq0.h[2] = pk2(a1.x * QSCALE, a1.y * QSCALE);
    uq0.h[3] = pk2(a1.z * QSCALE, a1.w * QSCALE);
    uq1.h[0] = pk2(a2.x * QSCALE, a2.y * QSCALE);
    uq1.h[1] = pk2(a2.z * QSCALE, a2.w * QSCALE);
    uq1.h[2] = pk2(a3.x * QSCALE, a3.y * QSCALE);
    uq1.h[3] = pk2(a3.z * QSCALE, a3.w * QSCALE);
    const f16x8 qf0 = uq0.v, qf1 = uq1.v;

    f32x4 o[4];
    #pragma unroll
    for (int mi = 0; mi < 4; ++mi) o[mi] = (f32x4){0.f, 0.f, 0.f, 0.f};
    float m_run = -1e30f, l_run = 0.f;

    const int t0 = (qrow0 > (WIN - 1)) ? (qrow0 - (WIN - 1)) >> 6 : 0;
    const int t1 = (qrow0 + BM - 1) >> 6;   // == qblk

    Pref pf;
    load_tile(pf, kb, vb, t0 * BN, row4, c4);
    stage_tile(smem, pf, row4, c4);
    __syncthreads();

    for (int t = t0; t <= t1; ++t) {
        const int cb = (t - t0) & 1;
        const _Float16* Kc = (const _Float16*)(smem + cb * BUFBYTES);
        const _Float16* Vc = (const _Float16*)(smem + cb * BUFBYTES + KBYTES);
        const bool have_next = (t < t1);

        if (have_next) load_tile(pf, kb, vb, (t + 1) * BN, row4, c4);
        __builtin_amdgcn_sched_barrier(0);   // pin prefetch issue point

        const int kbase = t * BN;
        // wave-uniform active m-tile range within this 64-key tile
        const int u    = (wr0 - kbase) >> 4;        // >= 0 for active tiles
        const int mtlo = (u - 32 > 0) ? u - 32 : 0;
        const int mthi = (u < 3) ? u : 3;

        if (mtlo <= mthi) {
            // ---- S^T = K * Q^T over active m-tiles ----
            f32x4 sc[4];
            #pragma unroll
            for (int mt = 0; mt < 4; ++mt) {
                if (mt >= mtlo && mt <= mthi) {
                    const f16x8 kf0 = *(const f16x8*)&Kc[(mt * 16 + lr) * KS + quad * 8];
                    const f16x8 kf1 = *(const f16x8*)&Kc[(mt * 16 + lr) * KS + 32 + quad * 8];
                    f32x4 s = (f32x4){0.f, 0.f, 0.f, 0.f};
                    s = __builtin_amdgcn_mfma_f32_16x16x32_f16(kf0, qf0, s, 0, 0, 0);
                    s = __builtin_amdgcn_mfma_f32_16x16x32_f16(kf1, qf1, s, 0, 0, 0);
                    sc[mt] = s;
                }
            }

            // ---- mask only on window-edge tiles (wave-uniform branch) ----
            const bool edge = (kbase + mtlo * 16 < wr0 + 15 - (WIN - 1)) ||
                              (kbase + mthi * 16 + 15 > wr0);
            if (edge) {
                #pragma unroll
                for (int mt = 0; mt < 4; ++mt) {
                    if (mt >= mtlo && mt <= mthi) {
                        #pragma unroll
                        for (int r = 0; r < 4; ++r) {
                            const int key = kbase + mt * 16 + quad * 4 + r;
                            sc[mt][r] = ((unsigned)(q - key) < (unsigned)WIN) ? sc[mt][r] : MASKVAL;
                        }
                    }
                }
            }

            // ---- shuffle-free common path: in-lane partial max + __any check.
            // __any(partial > m+THR) == __any(rowmax > m+THR): wave-wide OR of
            // per-lane partials covers the row max exactly. The 2 cross-lane
            // reduces run ONLY inside the rare rescale branch. Numerics identical.
            float pm = MASKVAL;
            #pragma unroll
            for (int mt = 0; mt < 4; ++mt) {
                if (mt >= mtlo && mt <= mthi) {
                    pm = fmaxf(pm, fmaxf(fmaxf(sc[mt][0], sc[mt][1]),
                                         fmaxf(sc[mt][2], sc[mt][3])));
                }
            }
            if (__any(pm > m_run + DEFER_THR)) {
                float pmf = pm;
                pmf = fmaxf(pmf, __shfl_xor(pmf, 16));
                pmf = fmaxf(pmf, __shfl_xor(pmf, 32));   // true row max
                const float mn    = fmaxf(m_run, pmf);
                const float alpha = exp2f(m_run - mn);
                m_run = mn;
                l_run *= alpha;
                #pragma unroll
                for (int mi = 0; mi < 4; ++mi) o[mi] = o[mi] * alpha;
            }

            f16x4 pb[4];
            float ls = 0.f;
            #pragma unroll
            for (int nt = 0; nt < 4; ++nt) {
                if (nt >= mtlo && nt <= mthi) {
                    const float p0 = exp2f(sc[nt][0] - m_run);
                    const float p1 = exp2f(sc[nt][1] - m_run);
                    const float p2 = exp2f(sc[nt][2] - m_run);
                    const float p3 = exp2f(sc[nt][3] - m_run);
                    ls += (p0 + p1) + (p2 + p3);
                    union { f16x4 v; f16x2 h[2]; } up;
                    up.h[0] = pk2(p0, p1);
                    up.h[1] = pk2(p2, p3);
                    pb[nt] = up.v;
                }
            }
            l_run += ls;

            // ---- O^T += V^T * P^T over active tiles (V from panels) ----
            #pragma unroll
            for (int nt = 0; nt < 4; ++nt) {
                if (nt >= mtlo && nt <= mthi) {
                    #pragma unroll
                    for (int mi = 0; mi < 4; ++mi) {
                        const f16x4 vf = *(const f16x4*)&Vc[nt * (DIM * VSP)
                                             + (mi * 16 + lr) * VSP + quad * 4];
                        o[mi] = __builtin_amdgcn_mfma_f32_16x16x16f16(vf, pb[nt], o[mi], 0, 0, 0);
                    }
                }
            }
        }

        // ---- stage t+1 into alternate buffer; ONE barrier per round ----
        if (have_next) stage_tile(smem + (cb ^ 1) * BUFBYTES, pf, row4, c4);
        __syncthreads();
    }

    // ---- epilogue: l reduce across quads, normalize, transpose via LDS, store ----
    l_run += __shfl_xor(l_run, 16);
    l_run += __shfl_xor(l_run, 32);
    const float inv = 1.0f / l_run;

    float* Ow = Osh + wave * 16 * OS;   // per-wave private 16 x OS region
    #pragma unroll
    for (int mi = 0; mi < 4; ++mi) {
        float4 st;
        st.x = o[mi][0] * inv; st.y = o[mi][1] * inv;
        st.z = o[mi][2] * inv; st.w = o[mi][3] * inv;
        *(float4*)&Ow[lr * OS + mi * 16 + quad * 4] = st;
    }
    #pragma unroll
    for (int j = 0; j < 4; ++j) {
        const int qq = quad + 4 * j;
        const int d4 = lr * 4;
        const float4 vst = *(const float4*)&Ow[qq * OS + d4];
        *(float4*)&ob[(size_t)(wr0 + qq) * DIM + d4] = vst;
    }
}

extern "C" void kernel_launch(void* const* d_in, const int* in_sizes, int n_in,
                              void* d_out, int out_size, void* d_ws, size_t ws_size,
                              hipStream_t stream) {
    (void)in_sizes; (void)n_in; (void)out_size; (void)d_ws; (void)ws_size;
    const float* q = (const float*)d_in[0];
    const float* k = (const float*)d_in[1];
    const float* v = (const float*)d_in[2];
    float* out = (float*)d_out;
    dim3 grid(SEQ / BM, BATCH);
    swa_kernel<<<grid, dim3(NTHREADS), 0, stream>>>(q, k, v, out);
}

// Round 11
// 116.000 us; speedup vs baseline: 1.0050x; 1.0050x over previous
//
#include <hip/hip_runtime.h>

#define BATCH 16
#define SEQ   4096
#define DIM   64
#define WIN   512

constexpr int BM = 64;        // q rows per block (4 waves x 16 q-rows)
constexpr int BN = 64;        // keys per tile
constexpr int NTHREADS = 256; // 4 waves
constexpr int NTILES = SEQ / BN;      // 64
constexpr int TILEB  = 8192;          // one 64x64 f16 tile (K or VT), swizzled
constexpr int BUFB   = 2 * TILEB;     // K + VT per buffer
constexpr int SMEMB  = 2 * BUFB;      // 32768 -> 4 blocks/CU (128KB/160KB)

constexpr float QSCALE  = 0.125f * 1.44269504088896340736f;
constexpr float MASKVAL = -3.0e38f;
constexpr float DEFER_THR = 8.0f;

typedef _Float16 f16x2 __attribute__((ext_vector_type(2)));
typedef _Float16 f16x4 __attribute__((ext_vector_type(4)));
typedef _Float16 f16x8 __attribute__((ext_vector_type(8)));
typedef float    f32x4 __attribute__((ext_vector_type(4)));

__device__ __forceinline__ f16x2 pk2(float a, float b) {
    return __builtin_bit_cast(f16x2, __builtin_amdgcn_cvt_pkrtz(a, b));
}

// global->LDS direct DMA, 16B per lane; LDS dest = (wave-uniform base) + lane*16
__device__ __forceinline__ void gl16(const char* g, char* l) {
    __builtin_amdgcn_global_load_lds(
        (const __attribute__((address_space(1))) unsigned int*)g,
        (__attribute__((address_space(3))) unsigned int*)l, 16, 0, 0);
}

// ---------------- pre-pass ----------------
// K16: [b][tile][64 rows][128B], 16B-chunk XOR-swizzled: chunk ^= (row&7)
// VT16: [b][tile][panel(key>>4)][64 d][16 key x 2B], 8B-chunk swz: j ^= (d>>2)&3
__global__ __launch_bounds__(256)
void prep_kernel(const float* __restrict__ kg, const float* __restrict__ vg,
                 _Float16* __restrict__ k16, _Float16* __restrict__ vt16) {
    const int t    = threadIdx.x;
    const int b    = blockIdx.y;
    const int tile = blockIdx.x;
    const int s0   = tile * 64;

    // K: 4 iters x (16 rows x 16 col-chunks)
    {
        const int rb    = t >> 4;            // 0..15
        const int c4    = (t & 15) * 4;      // 0..60
        const int chunk = c4 >> 3;           // 16B chunk index 0..7
        const int half  = (c4 >> 2) & 1;     // 8B half within chunk
        char* kout = (char*)k16 + ((size_t)b * NTILES + tile) * TILEB;
        #pragma unroll
        for (int i = 0; i < 4; ++i) {
            const int row = rb + i * 16;
            const float4 x = *(const float4*)&kg[((size_t)b * SEQ + s0 + row) * DIM + c4];
            union { f16x4 v; f16x2 h[2]; } u;
            u.h[0] = pk2(x.x, x.y); u.h[1] = pk2(x.z, x.w);
            *(f16x4*)(kout + row * 128 + ((chunk ^ (row & 7)) << 4) + half * 8) = u.v;
        }
    }
    // VT: thread -> d = t>>2, key-quad j = t&3; 4 panels
    {
        const int d   = t >> 2;              // 0..63
        const int j   = t & 3;               // key quad within panel
        const int swz = (j ^ ((d >> 2) & 3)) << 3;
        char* vout = (char*)vt16 + ((size_t)b * NTILES + tile) * TILEB;
        #pragma unroll
        for (int p = 0; p < 4; ++p) {
            const size_t kr = (size_t)b * SEQ + s0 + p * 16 + 4 * j;
            const float x0 = vg[(kr + 0) * DIM + d];
            const float x1 = vg[(kr + 1) * DIM + d];
            const float x2 = vg[(kr + 2) * DIM + d];
            const float x3 = vg[(kr + 3) * DIM + d];
            union { f16x4 v; f16x2 h[2]; } u;
            u.h[0] = pk2(x0, x1); u.h[1] = pk2(x2, x3);
            *(f16x4*)(vout + p * 2048 + d * 32 + swz) = u.v;
        }
    }
}

// ---------------- main ----------------
__global__ __launch_bounds__(NTHREADS, 4)
void swa_main(const float* __restrict__ qg, float* __restrict__ outg,
              const _Float16* __restrict__ k16, const _Float16* __restrict__ vt16) {
    __shared__ __align__(16) char smem[SMEMB];

    const int tid  = threadIdx.x;
    const int lane = tid & 63;
    const int wave = tid >> 6;     // 0..3
    const int lr   = lane & 15;
    const int quad = lane >> 4;

    // chunked XCD swizzle: 8 consecutive qblks of one batch per XCD chunk
    static_assert(SEQ / BM == 64 && BATCH == 16, "swizzle assumes 1024 blocks");
    const int lin    = blockIdx.x;         // 0..1023
    const int xcd    = lin & 7;
    const int slot   = lin >> 3;
    const int member = slot & 7;
    const int gchunk = (slot >> 3) * 8 + xcd;      // bijective
    const int b      = gchunk >> 3;
    const int qblk   = (gchunk & 7) * 8 + member;

    const int qrow0 = qblk * BM;
    const int wr0   = qrow0 + wave * 16;
    const int q     = wr0 + lr;

    const float* qb  = qg + (size_t)b * SEQ * DIM;
    float*       ob  = outg + (size_t)b * SEQ * DIM;
    const char*  kbb = (const char*)k16 + (size_t)b * NTILES * TILEB;
    const char*  vbb = (const char*)vt16 + (size_t)b * NTILES * TILEB;

    // swizzled LDS lane bases (computed once; loop offsets are immediates)
    const int kaddr0 = lr * 128 + (((quad    ) ^ (lr & 7)) << 4);  // chunks 0..3
    const int kaddr1 = lr * 128 + (((quad + 4) ^ (lr & 7)) << 4);  // chunks 4..7
    const int vaddr  = lr * 32 + ((quad ^ (lr >> 2)) << 3);
    const int dmaoff = wave * 1024 + lane * 16;                    // global src slice
    char* const ldsw = smem;  // per-buffer bases computed in loop

    // ---- Q B-frags straight from global into registers ----
    const float* qp = qb + (size_t)q * DIM + quad * 8;
    const float4 a0 = *(const float4*)(qp + 0);
    const float4 a1 = *(const float4*)(qp + 4);
    const float4 a2 = *(const float4*)(qp + 32);
    const float4 a3 = *(const float4*)(qp + 36);
    union { f16x8 v; f16x2 h[4]; } uq0, uq1;
    uq0.h[0] = pk2(a0.x * QSCALE, a0.y * QSCALE);
    uq0.h[1] = pk2(a0.z * QSCALE, a0.w * QSCALE);
    uq0.h[2] = pk2(a1.x * QSCALE, a1.y * QSCALE);
    uq0.h[3] = pk2(a1.z * QSCALE, a1.w * QSCALE);
    uq1.h[0] = pk2(a2.x * QSCALE, a2.y * QSCALE);
    uq1.h[1] = pk2(a2.z * QSCALE, a2.w * QSCALE);
    uq1.h[2] = pk2(a3.x * QSCALE, a3.y * QSCALE);
    uq1.h[3] = pk2(a3.z * QSCALE, a3.w * QSCALE);
    const f16x8 qf0 = uq0.v, qf1 = uq1.v;

    f32x4 o[4];
    #pragma unroll
    for (int mi = 0; mi < 4; ++mi) o[mi] = (f32x4){0.f, 0.f, 0.f, 0.f};
    float m_run = -1e30f, l_run = 0.f;

    const int t0 = (qrow0 > (WIN - 1)) ? (qrow0 - (WIN - 1)) >> 6 : 0;
    const int t1 = (qrow0 + BM - 1) >> 6;   // == qblk

    // ---- prologue: DMA tile t0 into buffer 0 (no VGPR, no convert) ----
    {
        const char* gK = kbb + (size_t)t0 * TILEB;
        const char* gV = vbb + (size_t)t0 * TILEB;
        gl16(gK + dmaoff,        ldsw + wave * 1024);
        gl16(gK + dmaoff + 4096, ldsw + wave * 1024 + 4096);
        gl16(gV + dmaoff,        ldsw + TILEB + wave * 1024);
        gl16(gV + dmaoff + 4096, ldsw + TILEB + wave * 1024 + 4096);
    }
    __syncthreads();

    for (int t = t0; t <= t1; ++t) {
        const int cb = (t - t0) & 1;
        const char* Kc = smem + cb * BUFB;
        const char* Vc = Kc + TILEB;

        // issue next tile's DMA into the alternate buffer FIRST; it completes
        // under this round's compute; __syncthreads at end waits vmcnt(0)
        if (t < t1) {
            char* nb = ldsw + (cb ^ 1) * BUFB;
            const char* gK = kbb + (size_t)(t + 1) * TILEB;
            const char* gV = vbb + (size_t)(t + 1) * TILEB;
            gl16(gK + dmaoff,        nb + wave * 1024);
            gl16(gK + dmaoff + 4096, nb + wave * 1024 + 4096);
            gl16(gV + dmaoff,        nb + TILEB + wave * 1024);
            gl16(gV + dmaoff + 4096, nb + TILEB + wave * 1024 + 4096);
        }

        const int kbase = t * BN;
        const int u     = (wr0 - kbase) >> 4;
        const int mtlo  = (u - 32 > 0) ? u - 32 : 0;
        const int mthi  = (u < 3) ? u : 3;

        if (mtlo <= mthi) {
            // ---- S^T = K * Q^T over active m-tiles (swizzled, conflict-free) ----
            f32x4 sc[4];
            #pragma unroll
            for (int mt = 0; mt < 4; ++mt) {
                if (mt >= mtlo && mt <= mthi) {
                    const f16x8 kf0 = *(const f16x8*)(Kc + mt * 2048 + kaddr0);
                    const f16x8 kf1 = *(const f16x8*)(Kc + mt * 2048 + kaddr1);
                    f32x4 s = (f32x4){0.f, 0.f, 0.f, 0.f};
                    s = __builtin_amdgcn_mfma_f32_16x16x32_f16(kf0, qf0, s, 0, 0, 0);
                    s = __builtin_amdgcn_mfma_f32_16x16x32_f16(kf1, qf1, s, 0, 0, 0);
                    sc[mt] = s;
                }
            }

            // ---- mask only window-edge tiles (wave-uniform branch) ----
            const bool edge = (kbase + mtlo * 16 < wr0 + 15 - (WIN - 1)) ||
                              (kbase + mthi * 16 + 15 > wr0);
            if (edge) {
                #pragma unroll
                for (int mt = 0; mt < 4; ++mt) {
                    if (mt >= mtlo && mt <= mthi) {
                        #pragma unroll
                        for (int r = 0; r < 4; ++r) {
                            const int key = kbase + mt * 16 + quad * 4 + r;
                            sc[mt][r] = ((unsigned)(q - key) < (unsigned)WIN) ? sc[mt][r] : MASKVAL;
                        }
                    }
                }
            }

            // ---- shuffle-free common-path online softmax (R9, verified) ----
            float pm = MASKVAL;
            #pragma unroll
            for (int mt = 0; mt < 4; ++mt) {
                if (mt >= mtlo && mt <= mthi) {
                    pm = fmaxf(pm, fmaxf(fmaxf(sc[mt][0], sc[mt][1]),
                                         fmaxf(sc[mt][2], sc[mt][3])));
                }
            }
            if (__any(pm > m_run + DEFER_THR)) {
                float pmf = pm;
                pmf = fmaxf(pmf, __shfl_xor(pmf, 16));
                pmf = fmaxf(pmf, __shfl_xor(pmf, 32));
                const float mn    = fmaxf(m_run, pmf);
                const float alpha = exp2f(m_run - mn);
                m_run = mn;
                l_run *= alpha;
                #pragma unroll
                for (int mi = 0; mi < 4; ++mi) o[mi] = o[mi] * alpha;
            }

            f16x4 pb[4];
            float ls = 0.f;
            #pragma unroll
            for (int nt = 0; nt < 4; ++nt) {
                if (nt >= mtlo && nt <= mthi) {
                    const float p0 = exp2f(sc[nt][0] - m_run);
                    const float p1 = exp2f(sc[nt][1] - m_run);
                    const float p2 = exp2f(sc[nt][2] - m_run);
                    const float p3 = exp2f(sc[nt][3] - m_run);
                    ls += (p0 + p1) + (p2 + p3);
                    union { f16x4 v; f16x2 h[2]; } up;
                    up.h[0] = pk2(p0, p1);
                    up.h[1] = pk2(p2, p3);
                    pb[nt] = up.v;
                }
            }
            l_run += ls;

            // ---- O^T += V^T * P^T (swizzled panels, conflict-free b64) ----
            #pragma unroll
            for (int nt = 0; nt < 4; ++nt) {
                if (nt >= mtlo && nt <= mthi) {
                    #pragma unroll
                    for (int mi = 0; mi < 4; ++mi) {
                        const f16x4 vf = *(const f16x4*)(Vc + nt * 2048 + mi * 512 + vaddr);
                        o[mi] = __builtin_amdgcn_mfma_f32_16x16x16f16(vf, pb[nt], o[mi], 0, 0, 0);
                    }
                }
            }
        }

        __syncthreads();   // waits own DMAs (vmcnt 0) + publishes buffer
    }

    // ---- epilogue: l reduce, normalize, direct stores (O^T rows contig in d) ----
    l_run += __shfl_xor(l_run, 16);
    l_run += __shfl_xor(l_run, 32);
    const float inv = 1.0f / l_run;
    #pragma unroll
    for (int mi = 0; mi < 4; ++mi) {
        float4 st;
        st.x = o[mi][0] * inv; st.y = o[mi][1] * inv;
        st.z = o[mi][2] * inv; st.w = o[mi][3] * inv;
        *(float4*)&ob[(size_t)q * DIM + mi * 16 + quad * 4] = st;
    }
}

extern "C" void kernel_launch(void* const* d_in, const int* in_sizes, int n_in,
                              void* d_out, int out_size, void* d_ws, size_t ws_size,
                              hipStream_t stream) {
    (void)in_sizes; (void)n_in; (void)out_size; (void)ws_size;
    const float* q = (const float*)d_in[0];
    const float* k = (const float*)d_in[1];
    const float* v = (const float*)d_in[2];
    float* out = (float*)d_out;

    const size_t KVB = (size_t)BATCH * SEQ * DIM * sizeof(_Float16);  // 8.39 MB
    _Float16* vt16 = (_Float16*)d_ws;                 // ws_size >= 16.8MB (proven R6)
    _Float16* k16  = (_Float16*)((char*)d_ws + KVB);

    prep_kernel<<<dim3(NTILES, BATCH), dim3(256), 0, stream>>>(k, v, k16, vt16);
    swa_main<<<dim3(BATCH * SEQ / BM), dim3(NTHREADS), 0, stream>>>(q, out, k16, vt16);
}